// Round 2
// baseline (170.005 us; speedup 1.0000x reference)
//
#include <hip/hip_runtime.h>

// Problem constants (fixed by reference).
#define TT   512
#define BB   2048
#define NTAG 16
#define CH   8              // timesteps staged per chunk
#define NCH  (TT / CH)      // 64 chunks
#define BBN  (BB * NTAG)

typedef float v2f __attribute__((ext_vector_type(2)));

// ---------- DPP helpers ----------
#define DPP_XOR1  0xB1    // quad_perm [1,0,3,2] : lane ^ 1
#define DPP_XOR2  0x4E    // quad_perm [2,3,0,1] : lane ^ 2
#define DPP_XOR3  0x1B    // quad_perm [3,2,1,0] : lane ^ 3
#define DPP_ROR4  0x124   // src gate g+3 == g-1 (verified round 2)
#define DPP_ROR8  0x128   // src gate g+2
#define DPP_ROR12 0x12C   // src gate g+1

template<int CTRL>
__device__ __forceinline__ float dppf(float v) {
    int r = __builtin_amdgcn_update_dpp(0, __builtin_bit_cast(int, v),
                                        CTRL, 0xF, 0xF, true);
    return __builtin_bit_cast(float, r);
}

// 3-wave producer/consumer split, 2 chains per producer wave:
//   wave 0     : recurrent scan for 8 batch elems as TWO interleaved
//                register-state sets (A: b0..b0+3, B: b0+4..b0+7). The two
//                chains are independent -> B's issue fills A's latency stalls.
//   waves 1,2  : per set: x staging, x-dot+bias (accx) precompute -> LDS,
//                and h -> projection + log_softmax -> global store.
// Producer reads accx (1 ds_read/step, prefetched), writes h (1 ds_write/step).
// One barrier per chunk; accx is produced one chunk ahead, h consumed one
// chunk behind. All FP math identical (same order) to the verified r1 kernel.
__global__ __launch_bounds__(192, 1) void qlstm_fused(
    const float* __restrict__ x,        // (T,B,8)
    const float* __restrict__ w_gates,  // (4,4,12)
    const float* __restrict__ b_gates,  // (4,4)
    const float* __restrict__ rx_theta, // (4,4)
    const float* __restrict__ w_tag,    // (16,4)
    const float* __restrict__ b_tag,    // (16,)
    float* __restrict__ out)            // (T,B,16)
{
    __shared__ float  accL[2][2][CH][64];   // [set][buf][step][lane] accx+bias
    __shared__ float  hrng[2][2][CH][64];   // [set][buf][step][lane] h ring
    __shared__ float4 xstg[2][2][64];       // [set][buf][lane] x staging

    const int tid = threadIdx.x;
    const int wv  = tid >> 6;          // 0 = producer, 1..2 = consumers
    const int l   = tid & 63;
    const int e   = l >> 4;
    const int g   = (l >> 2) & 3;
    const int k   = l & 3;

    const float IV  = 0.15915494309189535f;   // 1/(2pi): v_cos takes revolutions
    const float L2E = 1.44269504088896f;
    const float LN2 = 0.69314718056f;

    if (wv == 0) {
        // ============================ producer ============================
        const float* wrow = w_gates + (g * 4 + k) * 12;
        const float wh0 = wrow[8 + (k ^ 0)] * IV;
        const float wh1 = wrow[8 + (k ^ 1)] * IV;
        const float wh2 = wrow[8 + (k ^ 2)] * IV;
        const float wh3 = wrow[8 + (k ^ 3)] * IV;

        // Branchless gate activation: odd deg-7 poly act = ab + q*P(q^2).
        // g==2 -> tanh (refit, err<=2e-4); else sigmoid (Taylor, err~2e-5).
        const bool gt = (g == 2);
        const float ab = gt ? 0.0f : 0.5f;
        const float d0 = gt ? 0.999904f  : 0.25f;
        const float d1 = gt ? -0.331065f : -0.0208333333f;
        const float d2 = gt ? 0.120472f  : 0.00208333333f;
        const float d3 = gt ? -0.027717f : -2.10813e-4f;

        // tanh(c) deg-11 odd poly, |c| <= 2.0703 (bounded by construction).
        const float u0 = 0.999160f,  u1 = -0.325289f, u2 = 0.112257f;
        const float u3 = -0.028766f, u4 = 0.0043665f, u5 = -0.00028186f;

        const bool k0 = (k == 0), k1 = (k == 1), k3 = (k == 3);
        const bool g0 = (g == 0), g2 = (g == 2), glo = (g < 2);

        float hA = 0.f, h1A = 0.f, h2A = 0.f, h3A = 0.f, cA = 0.f;
        float hB = 0.f, h1B = 0.f, h2B = 0.f, h3B = 0.f, cB = 0.f;

        __syncthreads();               // P0: wait for accx(chunk 0)

        for (int cc = 0; cc < NCH; ++cc) {
            const int cur = cc & 1;
            const float* apA = &accL[0][cur][0][l];
            const float* apB = &accL[1][cur][0][l];
            float* hpA = &hrng[0][cur][0][l];
            float* hpB = &hrng[1][cur][0][l];

            float aA = apA[0];
            float aB = apB[0];

            #pragma unroll
            for (int i = 0; i < CH; ++i) {
                // prefetch next step's accx (off-chain; next chunk's step 0
                // is read after the barrier -- it isn't published yet here)
                float nA = aA, nB = aB;
                if (i + 1 < CH) {
                    nA = apA[(i + 1) * 64];
                    nB = apB[(i + 1) * 64];
                }

                // ---- dual interleaved step (A/B chains independent) ----
                float angA = fmaf(hA, wh0, aA);
                float angB = fmaf(hB, wh0, aB);
                angA = fmaf(h1A, wh1, angA);
                angB = fmaf(h1B, wh1, angB);
                angA = fmaf(h2A, wh2, angA);
                angB = fmaf(h2B, wh2, angB);
                angA = fmaf(h3A, wh3, angA);
                angB = fmaf(h3B, wh3, angB);

                const float CA = __builtin_amdgcn_cosf(angA);  // cos(2*pi*ang)
                const float CB = __builtin_amdgcn_cosf(angB);

                // wire-product via 3 parallel DPPs:
                // k0: m1*(m2*m3), k1: C*m1, k2: C*(m2*m3), k3: (C*m1)*(m2*m3)
                const float m1A = dppf<DPP_XOR1>(CA);
                const float m1B = dppf<DPP_XOR1>(CB);
                const float m2A = dppf<DPP_XOR2>(CA);
                const float m2B = dppf<DPP_XOR2>(CB);
                const float m3A = dppf<DPP_XOR3>(CA);
                const float m3B = dppf<DPP_XOR3>(CB);
                const float BpA = m2A * m3A;
                const float BpB = m2B * m3B;
                const float ppA = CA * m1A;
                const float ppB = CB * m1B;
                const float XA = k0 ? m1A : (k3 ? ppA : CA);
                const float XB = k0 ? m1B : (k3 ? ppB : CB);
                const float YA = k1 ? m1A : BpA;
                const float YB = k1 ? m1B : BpB;
                const float qA = XA * YA;                     // q in [-1,1]
                const float qB = XB * YB;

                // gate activation: odd deg-7 poly (valid on ALL lanes)
                const float yA  = qA * qA;
                const float yB  = qB * qB;
                const float y2A = yA * yA;
                const float y2B = yB * yB;
                const float paA = fmaf(yA, d1, d0);
                const float paB = fmaf(yB, d1, d0);
                const float pbA = fmaf(yA, d3, d2);
                const float pbB = fmaf(yB, d3, d2);
                const float PA  = fmaf(y2A, pbA, paA);
                const float PB  = fmaf(y2B, pbB, paB);
                const float actA = fmaf(qA, PA, ab);
                const float actB = fmaf(qB, PB, ab);

                // Role rotation: lane uses (act, g+1, g+2, g+3) as (f,i,g~,o).
                // Only g==0 lanes produce the TRUE c/h.
                const float rAA = dppf<DPP_ROR12>(actA);  // gate g+1
                const float rAB = dppf<DPP_ROR12>(actB);
                const float rBA = dppf<DPP_ROR8>(actA);   // gate g+2
                const float rBB = dppf<DPP_ROR8>(actB);
                const float rCA = dppf<DPP_ROR4>(actA);   // gate g+3
                const float rCB = dppf<DPP_ROR4>(actB);
                cA = fmaf(actA, cA, rAA * rBA);
                cB = fmaf(actB, cB, rAB * rBB);

                // tanh(c) deg-11 odd poly (Estrin); h_raw = (o*c)*P(c^2)
                const float cyA  = cA * cA;
                const float cyB  = cB * cB;
                const float cy2A = cyA * cyA;
                const float cy2B = cyB * cyB;
                const float t1A = fmaf(cyA, u1, u0);
                const float t1B = fmaf(cyB, u1, u0);
                const float t2A = fmaf(cyA, u3, u2);
                const float t2B = fmaf(cyB, u3, u2);
                const float t3A = fmaf(cyA, u5, u4);
                const float t3B = fmaf(cyB, u5, u4);
                const float t4A = fmaf(cy2A, t3A, t2A);
                const float t4B = fmaf(cy2B, t3B, t2B);
                const float PcA = fmaf(cy2A, t4A, t1A);
                const float PcB = fmaf(cy2B, t4B, t1B);
                const float vocA = rCA * cA;
                const float vocB = rCB * cB;
                const float hrA = PcA * vocA;
                const float hrB = PcB * vocB;

                // hand off h to consumer waves (true h on g==0 lanes)
                hpA[i * 64] = hrA;
                hpB[i * 64] = hrB;

                // redistribute TRUE h (g==0 lanes) to all gate quads
                const float r4A  = dppf<DPP_ROR4>(hrA);
                const float r4B  = dppf<DPP_ROR4>(hrB);
                const float r8A  = dppf<DPP_ROR8>(hrA);
                const float r8B  = dppf<DPP_ROR8>(hrB);
                const float r12A = dppf<DPP_ROR12>(hrA);
                const float r12B = dppf<DPP_ROR12>(hrB);
                hA = glo ? (g0 ? hrA : r4A) : (g2 ? r8A : r12A);
                hB = glo ? (g0 ? hrB : r4B) : (g2 ? r8B : r12B);

                // h gather within wire-quad (feeds next h-dot)
                h1A = dppf<DPP_XOR1>(hA);
                h1B = dppf<DPP_XOR1>(hB);
                h2A = dppf<DPP_XOR2>(hA);
                h2B = dppf<DPP_XOR2>(hB);
                h3A = dppf<DPP_XOR3>(hA);
                h3B = dppf<DPP_XOR3>(hB);

                aA = nA; aB = nB;
            }
            __syncthreads();           // publish h(cc); accx(cc+1) now ready
        }
    } else {
        // ============================ consumers ============================
        const int s  = wv - 1;                  // which state set we serve
        const int b0 = blockIdx.x * 8 + s * 4;

        const float* wrow = w_gates + (g * 4 + k) * 12;
        // packed x-weights (pairs match ds_read_b128 register adjacency)
        const v2f wp0 = { wrow[0] * IV, wrow[1] * IV };
        const v2f wp1 = { wrow[2] * IV, wrow[3] * IV };
        const v2f wp2 = { wrow[4] * IV, wrow[5] * IV };
        const v2f wp3 = { wrow[6] * IV, wrow[7] * IV };
        const v2f bp  = { (b_gates[g * 4 + k] + rx_theta[g * 4 + k]) * IV, 0.0f };

        // tag weights pre-scaled by log2(e): softmax runs in base 2
        const int tag = g * 4 + k;              // lane owns one output tag
        const float wt0 = w_tag[tag * 4 + (k ^ 0)] * L2E;
        const float wt1 = w_tag[tag * 4 + (k ^ 1)] * L2E;
        const float wt2 = w_tag[tag * 4 + (k ^ 2)] * L2E;
        const float wt3 = w_tag[tag * 4 + (k ^ 3)] * L2E;
        const float bt  = b_tag[tag] * L2E;

        const int hsl = e * 16 + k;             // g==0 slot of our (e,k)
        float* outp = out + (size_t)b0 * NTAG + l;   // 64 lanes = 256B per t

        // x staging: lane covers step (l>>3) of each chunk, 16B slot (l&7).
        const float* xlane = x + (size_t)(l >> 3) * (BB * 8)
                               + (size_t)b0 * 8 + (l & 7) * 4;
        const size_t CHOFF = (size_t)CH * BB * 8;

        // ---- prologue: x(0),x(1) -> LDS; accx(0) -> accL[s][0] ----
        float4 reg = *(const float4*)(xlane);
        xstg[s][0][l] = reg;
        reg = *(const float4*)(xlane + CHOFF);
        xstg[s][1][l] = reg;
        {
            float* ap = &accL[s][0][0][l];
            #pragma unroll
            for (int i = 0; i < CH; ++i) {
                const float4 xA = xstg[s][0][i * 8 + 2 * e];
                const float4 xB = xstg[s][0][i * 8 + 2 * e + 1];
                const v2f a01 = { xA.x, xA.y }, a23 = { xA.z, xA.w };
                const v2f a45 = { xB.x, xB.y }, a67 = { xB.z, xB.w };
                v2f acc = __builtin_elementwise_fma(a01, wp0, bp);
                acc = __builtin_elementwise_fma(a23, wp1, acc);
                acc = __builtin_elementwise_fma(a45, wp2, acc);
                acc = __builtin_elementwise_fma(a67, wp3, acc);
                ap[i * 64] = acc.x + acc.y;
            }
        }
        reg = *(const float4*)(xlane + 2 * CHOFF);   // x(2), latency hidden
        __syncthreads();               // P0

        for (int cc = 0; cc < NCH; ++cc) {
            const int cur = cc & 1;

            // stage x(cc+2) into its parity buffer (x(m) lives in buf m&1)
            if (cc + 2 < NCH) {
                xstg[s][cur][l] = reg;
                const int cn = (cc + 3 < NCH) ? cc + 3 : NCH - 1;
                reg = *(const float4*)(xlane + (size_t)cn * CHOFF);
            }

            // compute accx(cc+1) -> accL[s][cur^1] (producer reads it next chunk)
            if (cc + 1 < NCH) {
                float* ap = &accL[s][cur ^ 1][0][l];
                #pragma unroll
                for (int i = 0; i < CH; ++i) {
                    const float4 xA = xstg[s][cur ^ 1][i * 8 + 2 * e];
                    const float4 xB = xstg[s][cur ^ 1][i * 8 + 2 * e + 1];
                    const v2f a01 = { xA.x, xA.y }, a23 = { xA.z, xA.w };
                    const v2f a45 = { xB.x, xB.y }, a67 = { xB.z, xB.w };
                    v2f acc = __builtin_elementwise_fma(a01, wp0, bp);
                    acc = __builtin_elementwise_fma(a23, wp1, acc);
                    acc = __builtin_elementwise_fma(a45, wp2, acc);
                    acc = __builtin_elementwise_fma(a67, wp3, acc);
                    ap[i * 64] = acc.x + acc.y;
                }
            }

            // consume h(cc-1): projection + log_softmax + store
            if (cc > 0) {
                const float* hp = &hrng[s][cur ^ 1][0][hsl];
                #pragma unroll
                for (int i = 0; i < CH; ++i) {
                    // broadcast read (4 g-lanes share one address)
                    const float hv = hp[i * 64];
                    const float q1 = dppf<DPP_XOR1>(hv);
                    const float q2 = dppf<DPP_XOR2>(hv);
                    const float q3 = dppf<DPP_XOR3>(hv);

                    const float lgq = fmaf(hv, wt0, fmaf(q1, wt1, fmaf(q2, wt2,
                                         fmaf(q3, wt3, bt))));
                    const float ex = __builtin_amdgcn_exp2f(lgq);
                    float sm = ex + dppf<DPP_XOR1>(ex);
                    sm = sm + dppf<DPP_XOR2>(sm);
                    sm = sm + dppf<DPP_ROR4>(sm);
                    sm = sm + dppf<DPP_ROR8>(sm);
                    const float l2s = __builtin_amdgcn_logf(sm);   // log2(s)

                    *outp = (lgq - l2s) * LN2;
                    outp += BBN;
                }
            }
            __syncthreads();
        }

        // epilogue: drain h(63) (buffer 63&1 == 1)
        {
            const float* hp = &hrng[s][1][0][hsl];
            #pragma unroll
            for (int i = 0; i < CH; ++i) {
                const float hv = hp[i * 64];
                const float q1 = dppf<DPP_XOR1>(hv);
                const float q2 = dppf<DPP_XOR2>(hv);
                const float q3 = dppf<DPP_XOR3>(hv);

                const float lgq = fmaf(hv, wt0, fmaf(q1, wt1, fmaf(q2, wt2,
                                     fmaf(q3, wt3, bt))));
                const float ex = __builtin_amdgcn_exp2f(lgq);
                float sm = ex + dppf<DPP_XOR1>(ex);
                sm = sm + dppf<DPP_XOR2>(sm);
                sm = sm + dppf<DPP_ROR4>(sm);
                sm = sm + dppf<DPP_ROR8>(sm);
                const float l2s = __builtin_amdgcn_logf(sm);

                *outp = (lgq - l2s) * LN2;
                outp += BBN;
            }
        }
    }
}

extern "C" void kernel_launch(void* const* d_in, const int* in_sizes, int n_in,
                              void* d_out, int out_size, void* d_ws, size_t ws_size,
                              hipStream_t stream) {
    const float* x        = (const float*)d_in[0];
    const float* w_gates  = (const float*)d_in[1];
    const float* b_gates  = (const float*)d_in[2];
    const float* rx_theta = (const float*)d_in[3];
    const float* w_tag    = (const float*)d_in[4];
    const float* b_tag    = (const float*)d_in[5];
    float* out = (float*)d_out;

    qlstm_fused<<<BB / 8, 192, 0, stream>>>(x, w_gates, b_gates, rx_theta,
                                            w_tag, b_tag, out);
}

// Round 3
// 145.354 us; speedup vs baseline: 1.1696x; 1.1696x over previous
//
#include <hip/hip_runtime.h>

// Problem constants (fixed by reference).
#define TT   512
#define BB   2048
#define NTAG 16
#define CH   8              // timesteps staged per chunk
#define NCH  (TT / CH)      // 64 chunks
#define BBN  (BB * NTAG)

typedef float v2f __attribute__((ext_vector_type(2)));

// ---------- DPP helpers ----------
#define DPP_XOR1  0xB1    // quad_perm [1,0,3,2] : lane ^ 1
#define DPP_XOR2  0x4E    // quad_perm [2,3,0,1] : lane ^ 2
#define DPP_XOR3  0x1B    // quad_perm [3,2,1,0] : lane ^ 3
#define DPP_ROR4  0x124   // dst lane g gets src from gate g+3 (== g-1)
#define DPP_ROR8  0x128   // src gate g+2
#define DPP_ROR12 0x12C   // src gate g+1

template<int CTRL>
__device__ __forceinline__ float dppf(float v) {
    int r = __builtin_amdgcn_update_dpp(0, __builtin_bit_cast(int, v),
                                        CTRL, 0xF, 0xF, true);
    return __builtin_bit_cast(float, r);
}

// 4-wave producer/consumer split (round-1 topology + accx offload):
//   waves 0,1 : recurrent scan, one state set each (4 batch elems). Per chunk:
//               bulk-load 8 precomputed accx scalars (one waitcnt), then 8
//               steps of PURE VALU chain + one ds_write (h) each. No per-step
//               LDS reads -> no per-step lgkmcnt exposure on the chain.
//   waves 2,3 : per set: x staging, x-dot+bias (accx) precompute one chunk
//               AHEAD -> LDS, and h (one chunk BEHIND) -> projection +
//               log_softmax -> global store.
// Chain micro-opts vs r1 (all bit-identical on the value-carrying lanes):
//   * all-banks-true LSTM: roles (f,i,g~,o) selected from {act,rA,rB,rC}
//     before the c-update, so every lane computes the true c/h -> the
//     post-h redistribute (3 DPP + 3 cndmask, on-chain) is deleted.
//   * flattened wire-product selects (one less dependent level).
__global__ __launch_bounds__(256, 1) void qlstm_fused(
    const float* __restrict__ x,        // (T,B,8)
    const float* __restrict__ w_gates,  // (4,4,12)
    const float* __restrict__ b_gates,  // (4,4)
    const float* __restrict__ rx_theta, // (4,4)
    const float* __restrict__ w_tag,    // (16,4)
    const float* __restrict__ b_tag,    // (16,)
    float* __restrict__ out)            // (T,B,16)
{
    __shared__ float  accL[2][2][CH][64];   // [set][buf][step][lane] accx+bias
    __shared__ float  hrng[2][2][CH][64];   // [set][buf][step][lane] h ring
    __shared__ float4 xstg[2][2][64];       // [set][buf][lane] x staging

    const int tid = threadIdx.x;
    const int wv  = tid >> 6;          // 0,1 = producers; 2,3 = consumers
    const int l   = tid & 63;
    const int e   = l >> 4;
    const int g   = (l >> 2) & 3;
    const int k   = l & 3;

    const float IV  = 0.15915494309189535f;   // 1/(2pi): v_cos takes revolutions
    const float L2E = 1.44269504088896f;
    const float LN2 = 0.69314718056f;

    if (wv < 2) {
        // ============================ producer ============================
        const int s = wv;                       // state set

        const float* wrow = w_gates + (g * 4 + k) * 12;
        const float wh0 = wrow[8 + (k ^ 0)] * IV;
        const float wh1 = wrow[8 + (k ^ 1)] * IV;
        const float wh2 = wrow[8 + (k ^ 2)] * IV;
        const float wh3 = wrow[8 + (k ^ 3)] * IV;

        // Branchless gate activation: odd deg-7 poly act = ab + q*P(q^2).
        // g==2 -> tanh (refit, err<=2e-4); else sigmoid (Taylor, err~2e-5).
        const bool gt = (g == 2);
        const float ab = gt ? 0.0f : 0.5f;
        const float d0 = gt ? 0.999904f  : 0.25f;
        const float d1 = gt ? -0.331065f : -0.0208333333f;
        const float d2 = gt ? 0.120472f  : 0.00208333333f;
        const float d3 = gt ? -0.027717f : -2.10813e-4f;

        // tanh(c) deg-11 odd poly, |c| <= 2.0703 (bounded by construction).
        const float u0 = 0.999160f,  u1 = -0.325289f, u2 = 0.112257f;
        const float u3 = -0.028766f, u4 = 0.0043665f, u5 = -0.00028186f;

        const bool k0 = (k == 0), k1 = (k == 1), k3 = (k == 3);
        const bool g0 = (g == 0), g2 = (g == 2), glo = (g < 2);

        float h = 0.f, h1 = 0.f, h2 = 0.f, h3 = 0.f, c = 0.f;

        __syncthreads();               // P0: wait for accx(chunk 0)

        for (int cc = 0; cc < NCH; ++cc) {
            const int cur = cc & 1;

            // bulk-load this chunk's 8 accx scalars (one waitcnt, off-chain)
            const float* ap = &accL[s][cur][0][l];
            float a[CH];
            #pragma unroll
            for (int i = 0; i < CH; ++i) a[i] = ap[i * 64];

            float* hp = &hrng[s][cur][0][l];

            #pragma unroll
            for (int i = 0; i < CH; ++i) {
                // on-chain: h-dot as sequential fma string (h3 enters last)
                float ang = fmaf(h,  wh0, a[i]);
                ang = fmaf(h1, wh1, ang);
                ang = fmaf(h2, wh2, ang);
                ang = fmaf(h3, wh3, ang);

                const float C = __builtin_amdgcn_cosf(ang);   // cos(2*pi*ang)
                // wire-product via 3 parallel DPPs, flattened selects:
                // k0: m1*(m2*m3), k1: C*m1, k2: C*(m2*m3), k3: (C*m1)*(m2*m3)
                const float m1 = dppf<DPP_XOR1>(C);
                const float m2 = dppf<DPP_XOR2>(C);
                const float m3 = dppf<DPP_XOR3>(C);
                const float Bp  = m2 * m3;
                const float pp  = C * m1;
                const float F1  = k0 ? m1 : C;
                const float F1b = k3 ? pp : F1;
                const float F2  = k1 ? m1 : Bp;
                const float q   = F1b * F2;                   // q in [-1,1]

                // gate activation: odd deg-7 poly (valid on ALL lanes)
                const float y  = q * q;
                const float y2 = y * y;
                const float tA = fmaf(y, d1, d0);
                const float tB = fmaf(y, d3, d2);
                const float P  = fmaf(y2, tB, tA);
                const float act = fmaf(q, P, ab);

                // rotations: every lane sees all 4 gate activations
                const float rA = dppf<DPP_ROR12>(act);  // gate g+1
                const float rB = dppf<DPP_ROR8>(act);   // gate g+2
                const float rC = dppf<DPP_ROR4>(act);   // gate g+3
                // per-lane role selection -> TRUE (f,i,g~,o) on every bank.
                // bank0 picks (act,rA,rB,rC) exactly as the verified r1 code.
                const float f_ = glo ? (g0 ? act : rC) : (g2 ? rB : rA);
                const float i_ = glo ? (g0 ? rA : act) : (g2 ? rC : rB);
                const float gg = glo ? (g0 ? rB : rA) : (g2 ? act : rC);
                const float o_ = glo ? (g0 ? rC : rB) : (g2 ? rA : act);

                c = fmaf(f_, c, i_ * gg);

                // tanh(c) deg-11 odd poly (Estrin); h = (o*c)*P(c^2)
                const float cy  = c * c;
                const float cy2 = cy * cy;
                const float t1  = fmaf(cy, u1, u0);
                const float t2  = fmaf(cy, u3, u2);
                const float t3  = fmaf(cy, u5, u4);
                const float t4  = fmaf(cy2, t3, t2);
                const float Pc  = fmaf(cy2, t4, t1);
                const float voc = o_ * c;
                const float hr  = Pc * voc;

                // hand off h (true on all lanes now; consumer reads bank 0)
                hp[i * 64] = hr;

                // next-step h state: direct (no redistribute needed)
                h  = hr;
                h1 = dppf<DPP_XOR1>(hr);
                h2 = dppf<DPP_XOR2>(hr);
                h3 = dppf<DPP_XOR3>(hr);
            }
            __syncthreads();           // publish h(cc); accx(cc+1) now ready
        }
    } else {
        // ============================ consumers ============================
        const int s  = wv - 2;                  // which state set we serve
        const int b0 = blockIdx.x * 8 + s * 4;

        const float* wrow = w_gates + (g * 4 + k) * 12;
        // packed x-weights (pairs match ds_read_b128 register adjacency)
        const v2f wp0 = { wrow[0] * IV, wrow[1] * IV };
        const v2f wp1 = { wrow[2] * IV, wrow[3] * IV };
        const v2f wp2 = { wrow[4] * IV, wrow[5] * IV };
        const v2f wp3 = { wrow[6] * IV, wrow[7] * IV };
        const v2f bp  = { (b_gates[g * 4 + k] + rx_theta[g * 4 + k]) * IV, 0.0f };

        // tag weights pre-scaled by log2(e): softmax runs in base 2
        const int tag = g * 4 + k;              // lane owns one output tag
        const float wt0 = w_tag[tag * 4 + (k ^ 0)] * L2E;
        const float wt1 = w_tag[tag * 4 + (k ^ 1)] * L2E;
        const float wt2 = w_tag[tag * 4 + (k ^ 2)] * L2E;
        const float wt3 = w_tag[tag * 4 + (k ^ 3)] * L2E;
        const float bt  = b_tag[tag] * L2E;

        const int hsl = e * 16 + k;             // g==0 slot of our (e,k)
        float* outp = out + (size_t)b0 * NTAG + l;   // 64 lanes = 256B per t

        // x staging: lane covers step (l>>3) of each chunk, 16B slot (l&7).
        const float* xlane = x + (size_t)(l >> 3) * (BB * 8)
                               + (size_t)b0 * 8 + (l & 7) * 4;
        const size_t CHOFF = (size_t)CH * BB * 8;

        // ---- prologue: x(0),x(1) -> LDS; accx(0) -> accL[s][0] ----
        float4 reg = *(const float4*)(xlane);
        xstg[s][0][l] = reg;
        reg = *(const float4*)(xlane + CHOFF);
        xstg[s][1][l] = reg;
        {
            float* ap = &accL[s][0][0][l];
            #pragma unroll
            for (int i = 0; i < CH; ++i) {
                const float4 xA = xstg[s][0][i * 8 + 2 * e];
                const float4 xB = xstg[s][0][i * 8 + 2 * e + 1];
                const v2f a01 = { xA.x, xA.y }, a23 = { xA.z, xA.w };
                const v2f a45 = { xB.x, xB.y }, a67 = { xB.z, xB.w };
                v2f acc = __builtin_elementwise_fma(a01, wp0, bp);
                acc = __builtin_elementwise_fma(a23, wp1, acc);
                acc = __builtin_elementwise_fma(a45, wp2, acc);
                acc = __builtin_elementwise_fma(a67, wp3, acc);
                ap[i * 64] = acc.x + acc.y;
            }
        }
        reg = *(const float4*)(xlane + 2 * CHOFF);   // x(2), latency hidden
        __syncthreads();               // P0

        for (int cc = 0; cc < NCH; ++cc) {
            const int cur = cc & 1;

            // stage x(cc+2) into its parity buffer (x(m) lives in buf m&1)
            if (cc + 2 < NCH) {
                xstg[s][cur][l] = reg;
                const int cn = (cc + 3 < NCH) ? cc + 3 : NCH - 1;
                reg = *(const float4*)(xlane + (size_t)cn * CHOFF);
            }

            // compute accx(cc+1) -> accL[s][cur^1] (producer reads next chunk)
            if (cc + 1 < NCH) {
                float* ap = &accL[s][cur ^ 1][0][l];
                #pragma unroll
                for (int i = 0; i < CH; ++i) {
                    const float4 xA = xstg[s][cur ^ 1][i * 8 + 2 * e];
                    const float4 xB = xstg[s][cur ^ 1][i * 8 + 2 * e + 1];
                    const v2f a01 = { xA.x, xA.y }, a23 = { xA.z, xA.w };
                    const v2f a45 = { xB.x, xB.y }, a67 = { xB.z, xB.w };
                    v2f acc = __builtin_elementwise_fma(a01, wp0, bp);
                    acc = __builtin_elementwise_fma(a23, wp1, acc);
                    acc = __builtin_elementwise_fma(a45, wp2, acc);
                    acc = __builtin_elementwise_fma(a67, wp3, acc);
                    ap[i * 64] = acc.x + acc.y;
                }
            }

            // consume h(cc-1): projection + log_softmax + store
            if (cc > 0) {
                const float* hp = &hrng[s][cur ^ 1][0][hsl];
                #pragma unroll
                for (int i = 0; i < CH; ++i) {
                    // broadcast read (4 g-lanes share one address)
                    const float hv = hp[i * 64];
                    const float q1 = dppf<DPP_XOR1>(hv);
                    const float q2 = dppf<DPP_XOR2>(hv);
                    const float q3 = dppf<DPP_XOR3>(hv);

                    const float lgq = fmaf(hv, wt0, fmaf(q1, wt1, fmaf(q2, wt2,
                                         fmaf(q3, wt3, bt))));
                    const float ex = __builtin_amdgcn_exp2f(lgq);
                    float sm = ex + dppf<DPP_XOR1>(ex);
                    sm = sm + dppf<DPP_XOR2>(sm);
                    sm = sm + dppf<DPP_ROR4>(sm);
                    sm = sm + dppf<DPP_ROR8>(sm);
                    const float l2s = __builtin_amdgcn_logf(sm);   // log2(s)

                    *outp = (lgq - l2s) * LN2;
                    outp += BBN;
                }
            }
            __syncthreads();
        }

        // epilogue: drain h(63) (buffer 63&1 == 1)
        {
            const float* hp = &hrng[s][1][0][hsl];
            #pragma unroll
            for (int i = 0; i < CH; ++i) {
                const float hv = hp[i * 64];
                const float q1 = dppf<DPP_XOR1>(hv);
                const float q2 = dppf<DPP_XOR2>(hv);
                const float q3 = dppf<DPP_XOR3>(hv);

                const float lgq = fmaf(hv, wt0, fmaf(q1, wt1, fmaf(q2, wt2,
                                     fmaf(q3, wt3, bt))));
                const float ex = __builtin_amdgcn_exp2f(lgq);
                float sm = ex + dppf<DPP_XOR1>(ex);
                sm = sm + dppf<DPP_XOR2>(sm);
                sm = sm + dppf<DPP_ROR4>(sm);
                sm = sm + dppf<DPP_ROR8>(sm);
                const float l2s = __builtin_amdgcn_logf(sm);

                *outp = (lgq - l2s) * LN2;
                outp += BBN;
            }
        }
    }
}

extern "C" void kernel_launch(void* const* d_in, const int* in_sizes, int n_in,
                              void* d_out, int out_size, void* d_ws, size_t ws_size,
                              hipStream_t stream) {
    const float* x        = (const float*)d_in[0];
    const float* w_gates  = (const float*)d_in[1];
    const float* b_gates  = (const float*)d_in[2];
    const float* rx_theta = (const float*)d_in[3];
    const float* w_tag    = (const float*)d_in[4];
    const float* b_tag    = (const float*)d_in[5];
    float* out = (float*)d_out;

    qlstm_fused<<<BB / 8, 256, 0, stream>>>(x, w_gates, b_gates, rx_theta,
                                            w_tag, b_tag, out);
}